// Round 13
// baseline (1154.755 us; speedup 1.0000x reference)
//
#include <hip/hip_runtime.h>

#define B_ 16
#define S_ 512
#define T_ 2048
#define D_ 256
#define H_ 128

typedef _Float16 half2_t __attribute__((ext_vector_type(2)));
typedef _Float16 h8v __attribute__((ext_vector_type(8)));
typedef __attribute__((ext_vector_type(4))) float f4v;
union U32H2 { unsigned u; half2_t h; };
union U2H4 { uint2 u; _Float16 h[4]; };
union UH16 { _Float16 f; unsigned short u; };

// ---------------- workspace layout (floats) ----------------
#define WS_C     0          // c centers [B,S] : 8192
#define WS_W2    8192       // w2 [B,T] : 32768
#define WS_FRAG  40960      // Whh f16 MFMA B-frags [2 layers][131072 u16] = 262144 u16 (131072 floats)
#define WS_XG    303104     // Xg f16 [dir][s][n][b] : 8388608 u16 (4M floats)
#define WS_H1    8691712    // H [b][s][256] fp32 : 2097152

// ---------------- output layout (floats) ----------------
#define OUT_MAIN   0          // [B,T,D]  8388608
#define OUT_LOGDUR 8388608    // [B,S]    8192
#define OUT_DUR    8396800    // [B,S]    8192
#define OUT_W      8404992    // [B,S,T]  16777216

// s_waitcnt imm: lgkmcnt(0), vmcnt(63)=no-wait, expcnt(7)=no-wait (gfx9 encoding)
#define WAIT_LGKM0_ONLY 0xC07F

__device__ __forceinline__ float sigf(float x) {
    return __builtin_amdgcn_rcpf(1.f + __expf(-x));
}
__device__ __forceinline__ float tanhfast(float x) {
    float xc = fmaxf(x, -15.f);
    return __builtin_fmaf(2.f, __builtin_amdgcn_rcpf(1.f + __expf(-2.f * xc)), -1.f);
}
__device__ __forceinline__ unsigned packh2(float a, float b) {
    U32H2 u; u.h = half2_t{(_Float16)a, (_Float16)b}; return u.u;
}

// ============ prep: cumsum -> centers, copy duration ============
__global__ void prep_kernel(const float* __restrict__ dur, float* __restrict__ c,
                            float* __restrict__ out_dur) {
    int b = blockIdx.x;
    int s = threadIdx.x;
    __shared__ float sc[S_];
    float d = dur[b * S_ + s];
    sc[s] = d;
    __syncthreads();
    float v = d;
    for (int off = 1; off < S_; off <<= 1) {
        float add = (s >= off) ? sc[s - off] : 0.f;
        __syncthreads();
        v += add;
        sc[s] = v;
        __syncthreads();
    }
    c[b * S_ + s] = v - 0.5f * d;
    out_dur[b * S_ + s] = d;
}

// ============ Whh -> f16 MFMA B-fragments ============
// frag[layer][dir][tn][kc][l][j] = Whh[layer][dir][n=tn*16+(l&15)][k=kc*32+(l>>4)*8+j]
// (identical geometry to round-2's bf16 version, which passed correctness)
__global__ void whh_frag_kernel(const float* __restrict__ Whh0, const float* __restrict__ Whh1,
                                unsigned short* __restrict__ frags) {
    int idx = blockIdx.x * 256 + threadIdx.x;  // 262144
    int j = idx & 7, l = (idx >> 3) & 63, kc = (idx >> 9) & 3, tn = (idx >> 11) & 31;
    int dir = (idx >> 16) & 1, layer = (idx >> 17) & 1;
    int n = tn * 16 + (l & 15);
    int k = kc * 32 + (l >> 4) * 8 + j;
    const float* W = layer ? Whh1 : Whh0;
    UH16 u; u.f = (_Float16)W[dir * 65536 + n * 128 + k];
    frags[idx] = u.u;
}

// ============ gemm: Xgh[((dir*512+s)*512+jj)*16+b] = f16(A[m,:256].Wih[n,:256]+bias) ============
// A rows m = b*512+s  (x is [B,S,256]; H1 is [b][s][256] -> same row order)
#define BM 64
#define BN 64
#define BK 64
__global__ __launch_bounds__(256) void gemm_xg_kernel(const float* __restrict__ A,
                                                      const float* __restrict__ Bw,
                                                      const float* __restrict__ bias,
                                                      unsigned short* __restrict__ Xgh) {
    __shared__ float As[BK][BM + 4];
    __shared__ float Bs[BK][BN + 4];
    int tid = threadIdx.x;
    int m0 = blockIdx.x * BM;
    int n0 = blockIdx.y * BN;
    int tm = tid >> 4, tn = tid & 15;
    float acc[4][4] = {};
    for (int k0 = 0; k0 < 256; k0 += BK) {
#pragma unroll
        for (int i = 0; i < 4; i++) {
            int p = tid + 256 * i;
            int m = p >> 4, kq = p & 15;
            float4 av = *reinterpret_cast<const float4*>(&A[(size_t)(m0 + m) * 256 + k0 + 4 * kq]);
            As[4 * kq + 0][m] = av.x; As[4 * kq + 1][m] = av.y;
            As[4 * kq + 2][m] = av.z; As[4 * kq + 3][m] = av.w;
            float4 bv = *reinterpret_cast<const float4*>(&Bw[(size_t)(n0 + m) * 256 + k0 + 4 * kq]);
            Bs[4 * kq + 0][m] = bv.x; Bs[4 * kq + 1][m] = bv.y;
            Bs[4 * kq + 2][m] = bv.z; Bs[4 * kq + 3][m] = bv.w;
        }
        __syncthreads();
#pragma unroll
        for (int k = 0; k < BK; k++) {
            float4 a4 = *reinterpret_cast<const float4*>(&As[k][4 * tm]);
            float4 b4 = *reinterpret_cast<const float4*>(&Bs[k][4 * tn]);
            float av[4] = {a4.x, a4.y, a4.z, a4.w};
            float bv[4] = {b4.x, b4.y, b4.z, b4.w};
#pragma unroll
            for (int i = 0; i < 4; i++)
#pragma unroll
                for (int j = 0; j < 4; j++) acc[i][j] += av[i] * bv[j];
        }
        __syncthreads();
    }
#pragma unroll
    for (int i = 0; i < 4; i++) {
        int m = m0 + 4 * tm + i;
        int b = m >> 9, s = m & 511;
#pragma unroll
        for (int jx = 0; jx < 4; jx++) {
            int n = n0 + 4 * tn + jx;
            int dir = n >> 9, jj = n & 511;
            UH16 u; u.f = (_Float16)(acc[i][jx] + bias[n]);
            Xgh[((size_t)(dir * 512 + s) * 512 + jj) * 16 + b] = u.u;
        }
    }
}

// ============ MFMA LSTM scan body: one block per dir, all 16 batches ============
// G[16,512] = H[16,128] @ WhhT per step via 16 mfma_f32_16x16x32_f16 per wave.
// Wave w owns gate tiles {w, 8+w, 16+w, 24+w} -> lane holds i,f,g,o for (batch,hcol) in regs.
__device__ void lstm_scan_body(const unsigned short* __restrict__ Xgh,
                               const unsigned short* __restrict__ frags,
                               float* __restrict__ Hout, char* smem, int dir) {
    int tid = threadIdx.x;
    int w = tid >> 6, l = tid & 63;
    int col = l & 15, lg = l >> 4;

    // B-fragments: 16 x 16B = 64 VGPRs via opaque asm (residency proven r8/r10/r11)
    uint4 bf00, bf01, bf02, bf03, bf10, bf11, bf12, bf13;
    uint4 bf20, bf21, bf22, bf23, bf30, bf31, bf32, bf33;
    {
        const unsigned short* p0 = frags + ((size_t)(dir * 32 + 0 * 8 + w) * 4) * 512 + l * 8;
        const unsigned short* p1 = frags + ((size_t)(dir * 32 + 1 * 8 + w) * 4) * 512 + l * 8;
        const unsigned short* p2 = frags + ((size_t)(dir * 32 + 2 * 8 + w) * 4) * 512 + l * 8;
        const unsigned short* p3 = frags + ((size_t)(dir * 32 + 3 * 8 + w) * 4) * 512 + l * 8;
#define FL(W, P, OFF) \
    asm volatile("global_load_dwordx4 %0, %1, off offset:" #OFF : "=v"(W) : "v"(P) : "memory")
        FL(bf00, p0, 0); FL(bf01, p0, 1024); FL(bf02, p0, 2048); FL(bf03, p0, 3072);
        FL(bf10, p1, 0); FL(bf11, p1, 1024); FL(bf12, p1, 2048); FL(bf13, p1, 3072);
        FL(bf20, p2, 0); FL(bf21, p2, 1024); FL(bf22, p2, 2048); FL(bf23, p2, 3072);
        FL(bf30, p3, 0); FL(bf31, p3, 1024); FL(bf32, p3, 2048); FL(bf33, p3, 3072);
#undef FL
    }
    asm volatile("s_waitcnt vmcnt(0)" ::: "memory");

    unsigned short* hb = (unsigned short*)smem;  // [2][16][136] f16 double-buffered
    for (int i = tid; i < 2 * 16 * 136; i += 512) hb[i] = 0;

    // xg pointers: lane needs G-init for n_g = g*128 + w*16 + col, batches lg*4..lg*4+3 (f16 x4)
    ptrdiff_t sstep = dir ? -8192 : 8192;  // u16 per s-slice
    int s0 = dir ? 511 : 0;
    const unsigned short* xp0 = Xgh + ((size_t)(dir * 512 + s0) * 512 + 0 * 128 + w * 16 + col) * 16 + lg * 4;
    const unsigned short* xp1 = xp0 + 128 * 16;
    const unsigned short* xp2 = xp0 + 256 * 16;
    const unsigned short* xp3 = xp0 + 384 * 16;
    uint2 xc0 = *(const uint2*)xp0, xc1 = *(const uint2*)xp1;
    uint2 xc2 = *(const uint2*)xp2, xc3 = *(const uint2*)xp3;
    xp0 += sstep; xp1 += sstep; xp2 += sstep; xp3 += sstep;

    float* ho_p = Hout + ((size_t)(lg * 4) * 512 + s0) * 256 + dir * 128 + w * 16 + col;
    ptrdiff_t hostep = dir ? -256 : 256;
    f4v c4 = {0.f, 0.f, 0.f, 0.f};
    __syncthreads();

    const unsigned short* hbr_base = hb + col * 136 + lg * 8;  // A: row=batch=col(l&15), k=lg*8+j

#define CVT4(DST, SRC) { U2H4 t_; t_.u = SRC; \
    DST[0] = (float)t_.h[0]; DST[1] = (float)t_.h[1]; \
    DST[2] = (float)t_.h[2]; DST[3] = (float)t_.h[3]; }

    for (int t = 0; t < 512; t++) {
        // prefetch next-step xg (4 x 8B loads; never drained in-loop)
        uint2 xn0 = *(const uint2*)xp0; xp0 += sstep;
        uint2 xn1 = *(const uint2*)xp1; xp1 += sstep;
        uint2 xn2 = *(const uint2*)xp2; xp2 += sstep;
        uint2 xn3 = *(const uint2*)xp3; xp3 += sstep;

        f4v acc0, acc1, acc2, acc3;
        CVT4(acc0, xc0) CVT4(acc1, xc1) CVT4(acc2, xc2) CVT4(acc3, xc3)

        const unsigned short* hbr = hbr_base + (t & 1) * 2176;
        // kc 0/1
        h8v a0 = *(const h8v*)(hbr);
        h8v a1 = *(const h8v*)(hbr + 32);
        acc0 = __builtin_amdgcn_mfma_f32_16x16x32_f16(a0, __builtin_bit_cast(h8v, bf00), acc0, 0, 0, 0);
        acc1 = __builtin_amdgcn_mfma_f32_16x16x32_f16(a0, __builtin_bit_cast(h8v, bf10), acc1, 0, 0, 0);
        acc2 = __builtin_amdgcn_mfma_f32_16x16x32_f16(a0, __builtin_bit_cast(h8v, bf20), acc2, 0, 0, 0);
        acc3 = __builtin_amdgcn_mfma_f32_16x16x32_f16(a0, __builtin_bit_cast(h8v, bf30), acc3, 0, 0, 0);
        acc0 = __builtin_amdgcn_mfma_f32_16x16x32_f16(a1, __builtin_bit_cast(h8v, bf01), acc0, 0, 0, 0);
        acc1 = __builtin_amdgcn_mfma_f32_16x16x32_f16(a1, __builtin_bit_cast(h8v, bf11), acc1, 0, 0, 0);
        acc2 = __builtin_amdgcn_mfma_f32_16x16x32_f16(a1, __builtin_bit_cast(h8v, bf21), acc2, 0, 0, 0);
        acc3 = __builtin_amdgcn_mfma_f32_16x16x32_f16(a1, __builtin_bit_cast(h8v, bf31), acc3, 0, 0, 0);
        // kc 2/3
        h8v a2 = *(const h8v*)(hbr + 64);
        h8v a3 = *(const h8v*)(hbr + 96);
        acc0 = __builtin_amdgcn_mfma_f32_16x16x32_f16(a2, __builtin_bit_cast(h8v, bf02), acc0, 0, 0, 0);
        acc1 = __builtin_amdgcn_mfma_f32_16x16x32_f16(a2, __builtin_bit_cast(h8v, bf12), acc1, 0, 0, 0);
        acc2 = __builtin_amdgcn_mfma_f32_16x16x32_f16(a2, __builtin_bit_cast(h8v, bf22), acc2, 0, 0, 0);
        acc3 = __builtin_amdgcn_mfma_f32_16x16x32_f16(a2, __builtin_bit_cast(h8v, bf32), acc3, 0, 0, 0);
        acc0 = __builtin_amdgcn_mfma_f32_16x16x32_f16(a3, __builtin_bit_cast(h8v, bf03), acc0, 0, 0, 0);
        acc1 = __builtin_amdgcn_mfma_f32_16x16x32_f16(a3, __builtin_bit_cast(h8v, bf13), acc1, 0, 0, 0);
        acc2 = __builtin_amdgcn_mfma_f32_16x16x32_f16(a3, __builtin_bit_cast(h8v, bf23), acc2, 0, 0, 0);
        acc3 = __builtin_amdgcn_mfma_f32_16x16x32_f16(a3, __builtin_bit_cast(h8v, bf33), acc3, 0, 0, 0);

        // cell update: lane holds i=acc0[r], f=acc1[r], g=acc2[r], o=acc3[r]
        // for batch=lg*4+r, hcol=w*16+col. Pure-register, no act exchange.
        unsigned short* hbw = hb + ((t + 1) & 1) * 2176 + w * 16 + col;
#pragma unroll
        for (int r = 0; r < 4; r++) {
            float cn = sigf(acc1[r]) * c4[r] + sigf(acc0[r]) * tanhfast(acc2[r]);
            c4[r] = cn;
            float h = sigf(acc3[r]) * tanhfast(cn);
            UH16 hv; hv.f = (_Float16)h;
            hbw[(lg * 4 + r) * 136] = hv.u;
            ho_p[(size_t)r * (512 * 256)] = h;
        }
        ho_p += hostep;

        // drain-free step sync (r11-proven): LDS-only wait + raw barrier
        __builtin_amdgcn_sched_barrier(0);
        __builtin_amdgcn_s_waitcnt(WAIT_LGKM0_ONLY);
        __builtin_amdgcn_s_barrier();
        __builtin_amdgcn_sched_barrier(0);
        xc0 = xn0; xc1 = xn1; xc2 = xn2; xc3 = xn3;
    }
#undef CVT4
}

// ============ w-write body (fused into layer-0 scan launch) ============
__device__ void wwrite_body(const float* __restrict__ c, const float* __restrict__ w2,
                            float* __restrict__ wout, int gb) {
    int base = (gb * 512 + (int)threadIdx.x) * 8;
    int t0 = base & 2047;
    int bs = base >> 11;
    int b = bs >> 9;
    float cv = c[bs];
    float4 w2a = *(const float4*)&w2[b * 2048 + t0];
    float4 w2b = *(const float4*)&w2[b * 2048 + t0 + 4];
    float r[8];
#pragma unroll
    for (int i = 0; i < 8; i++) {
        float d = (float)(t0 + 1 + i) - cv;
        r[i] = __expf(-0.1f * d * d);
    }
    float4 o1 = {r[0] / w2a.x, r[1] / w2a.y, r[2] / w2a.z, r[3] / w2a.w};
    float4 o2 = {r[4] / w2b.x, r[5] / w2b.y, r[6] / w2b.z, r[7] / w2b.w};
    *(float4*)&wout[base] = o1;
    *(float4*)&wout[base + 4] = o2;
}

// ============ einsum GEMM body: f16-pair fdot2, 128(t)x64(d) tile, K=512 ============
__device__ void gemm_out_body(const float* __restrict__ wmat, const float* __restrict__ x,
                              float* __restrict__ out, int gb, char* smem) {
    int tt = gb & 15, dd = (gb >> 4) & 3, b = gb >> 6;
    int m0 = tt * 128, n0 = dd * 64;
    unsigned* As2 = (unsigned*)smem;       // [32][136]
    unsigned* Bs2 = As2 + 32 * 136;        // [32][72]
    const float* wb = wmat + (size_t)b * (512 * 2048);
    const float* xb = x + (size_t)b * (512 * 256);
    int tid = threadIdx.x;
    int tm = tid >> 4, tn = tid & 15;
    float acc[4][4] = {};
    for (int k0 = 0; k0 < 512; k0 += 64) {
#pragma unroll
        for (int i = 0; i < 2; i++) {
            int p = tid + 512 * i;
            int k2 = p >> 5, mq = p & 31;
            float4 lo = *(const float4*)&wb[(size_t)(k0 + 2 * k2) * 2048 + m0 + 4 * mq];
            float4 hi = *(const float4*)&wb[(size_t)(k0 + 2 * k2 + 1) * 2048 + m0 + 4 * mq];
            uint4 o;
            o.x = packh2(lo.x, hi.x); o.y = packh2(lo.y, hi.y);
            o.z = packh2(lo.z, hi.z); o.w = packh2(lo.w, hi.w);
            *(uint4*)&As2[k2 * 136 + 4 * mq] = o;
        }
        {
            int k2 = tid >> 4, nq = tid & 15;
            float4 lo = *(const float4*)&xb[(size_t)(k0 + 2 * k2) * 256 + n0 + 4 * nq];
            float4 hi = *(const float4*)&xb[(size_t)(k0 + 2 * k2 + 1) * 256 + n0 + 4 * nq];
            uint4 o;
            o.x = packh2(lo.x, hi.x); o.y = packh2(lo.y, hi.y);
            o.z = packh2(lo.z, hi.z); o.w = packh2(lo.w, hi.w);
            *(uint4*)&Bs2[k2 * 72 + 4 * nq] = o;
        }
        __syncthreads();
#pragma unroll
        for (int k2 = 0; k2 < 32; k2++) {
            uint4 a4 = *(const uint4*)&As2[k2 * 136 + 4 * tm];
            uint4 b4 = *(const uint4*)&Bs2[k2 * 72 + 4 * tn];
            U32H2 aa0, aa1, aa2, aa3, bb0, bb1, bb2, bb3;
            aa0.u = a4.x; aa1.u = a4.y; aa2.u = a4.z; aa3.u = a4.w;
            bb0.u = b4.x; bb1.u = b4.y; bb2.u = b4.z; bb3.u = b4.w;
            half2_t av[4] = {aa0.h, aa1.h, aa2.h, aa3.h};
            half2_t bv[4] = {bb0.h, bb1.h, bb2.h, bb3.h};
#pragma unroll
            for (int i = 0; i < 4; i++)
#pragma unroll
                for (int j = 0; j < 4; j++)
                    acc[i][j] = __builtin_amdgcn_fdot2(av[i], bv[j], acc[i][j], false);
        }
        __syncthreads();
    }
#pragma unroll
    for (int i = 0; i < 4; i++) {
        int m = m0 + 4 * tm + i;
        float4 o = {acc[i][0], acc[i][1], acc[i][2], acc[i][3]};
        *(float4*)&out[((size_t)b * 2048 + m) * 256 + n0 + 4 * tn] = o;
    }
}

// ============ fused launches: 2 MFMA-scan blocks + fillers, 2 waves/EU cap ============
__global__ __launch_bounds__(512) __attribute__((amdgpu_waves_per_eu(2, 2)))
void fusedA_kernel(const unsigned short* __restrict__ Xgh, const unsigned short* __restrict__ frags,
                   float* __restrict__ H1, const float* __restrict__ c,
                   const float* __restrict__ w2, float* __restrict__ out_w) {
    extern __shared__ char smem[];
    if (blockIdx.x < 2) lstm_scan_body(Xgh, frags, H1, smem, blockIdx.x);
    else wwrite_body(c, w2, out_w, blockIdx.x - 2);
}

__global__ __launch_bounds__(512) __attribute__((amdgpu_waves_per_eu(2, 2)))
void fusedB_kernel(const unsigned short* __restrict__ Xgh, const unsigned short* __restrict__ frags,
                   float* __restrict__ H1, const float* __restrict__ wmat,
                   const float* __restrict__ x, float* __restrict__ out_main) {
    extern __shared__ char smem[];
    if (blockIdx.x < 2) lstm_scan_body(Xgh, frags, H1, smem, blockIdx.x);
    else gemm_out_body(wmat, x, out_main, blockIdx.x - 2, smem);
}

// ============ projection: log_dur (H1 [b][s][256]) ============
__global__ void proj_kernel(const float* __restrict__ H2, const float* __restrict__ pw,
                            const float* __restrict__ pb, const unsigned char* __restrict__ mask,
                            float* __restrict__ out) {
    int row = blockIdx.x * 4 + (threadIdx.x >> 6);
    int lane = threadIdx.x & 63;
    float4 h = *reinterpret_cast<const float4*>(&H2[(size_t)row * 256 + lane * 4]);
    float4 w = *reinterpret_cast<const float4*>(&pw[lane * 4]);
    float v = h.x * w.x + h.y * w.y + h.z * w.z + h.w * w.w;
#pragma unroll
    for (int off = 32; off; off >>= 1) v += __shfl_xor(v, off);
    if (lane == 0) {
        float r = v + pb[0];
        r = r > 0.f ? r : 0.f;
        if (mask[row]) r = 0.f;
        out[row] = r;
    }
}

// ============ w2[b,t] = sum_s exp(-0.1 (t+1-c)^2) ============
__global__ void wsum_kernel(const float* __restrict__ c, float* __restrict__ w2) {
    int idx = blockIdx.x * 4 + (threadIdx.x >> 6);
    int lane = threadIdx.x & 63;
    int b = idx >> 11, t = idx & 2047;
    float tv = (float)(t + 1);
    const float* cb = c + b * 512;
    float sum = 0.f;
#pragma unroll
    for (int i = 0; i < 8; i++) {
        float d = tv - cb[lane + 64 * i];
        sum += __expf(-0.1f * d * d);
    }
#pragma unroll
    for (int off = 32; off; off >>= 1) sum += __shfl_xor(sum, off);
    if (lane == 0) w2[idx] = (sum == 0.f) ? 1.f : sum;
}

extern "C" void kernel_launch(void* const* d_in, const int* in_sizes, int n_in,
                              void* d_out, int out_size, void* d_ws, size_t ws_size,
                              hipStream_t stream) {
    const float* x = (const float*)d_in[0];
    const unsigned char* mask = (const unsigned char*)d_in[1];
    const float* dur = (const float*)d_in[2];
    const float* Wih0 = (const float*)d_in[3];
    const float* Whh0 = (const float*)d_in[4];
    const float* b0 = (const float*)d_in[5];
    const float* Wih1 = (const float*)d_in[6];
    const float* Whh1 = (const float*)d_in[7];
    const float* b1 = (const float*)d_in[8];
    const float* pw = (const float*)d_in[9];
    const float* pb = (const float*)d_in[10];

    float* out = (float*)d_out;
    float* ws = (float*)d_ws;
    float* c = ws + WS_C;
    float* w2 = ws + WS_W2;
    unsigned short* frags = (unsigned short*)(ws + WS_FRAG);
    unsigned short* Xgh = (unsigned short*)(ws + WS_XG);
    float* H1 = ws + WS_H1;

    float* out_main = out + OUT_MAIN;
    float* out_logdur = out + OUT_LOGDUR;
    float* out_dur = out + OUT_DUR;
    float* out_w = out + OUT_W;

    // ---- prep: centers, duration copy, Whh f16 fragments, w2 ----
    prep_kernel<<<16, 512, 0, stream>>>(dur, c, out_dur);
    whh_frag_kernel<<<1024, 256, 0, stream>>>(Whh0, Whh1, frags);
    wsum_kernel<<<8192, 256, 0, stream>>>(c, w2);

    // ---- layer 0: Xg gemm (A = x), then MFMA scan fused with w-write ----
    gemm_xg_kernel<<<dim3(128, 16), 256, 0, stream>>>(x, Wih0, b0, Xgh);
    fusedA_kernel<<<2 + 4096, 512, 8704, stream>>>(Xgh, frags, H1, c, w2, out_w);

    // ---- layer 1: Xg gemm (A = H1, same row order), then MFMA scan + f16 einsum ----
    gemm_xg_kernel<<<dim3(128, 16), 256, 0, stream>>>(H1, Wih1, b1, Xgh);
    fusedB_kernel<<<2 + 1024, 512, 26624, stream>>>(Xgh, frags + 131072, H1, out_w, x, out_main);

    // ---- projection ----
    proj_kernel<<<2048, 256, 0, stream>>>(H1, pw, pb, mask, out_logdur);
}

// Round 14
// 656.581 us; speedup vs baseline: 1.7587x; 1.7587x over previous
//
#include <hip/hip_runtime.h>

#define B_ 16
#define S_ 512
#define T_ 2048
#define D_ 256
#define H_ 128

typedef _Float16 half2_t __attribute__((ext_vector_type(2)));
union U32H2 { unsigned u; half2_t h; };
union UH16 { _Float16 f; unsigned short u; };

// ---------------- workspace layout (floats) ----------------
#define WS_C     0          // c centers [B,S] : 8192
#define WS_W2    8192       // w2 [B,T] : 32768
#define WS_WPK   40960      // Whh f16-pair pack [2 layers][65536 uint] : 131072 uints
#define WS_XG    303104     // Xg [dir][s][b][512] fp32 : 8388608
#define WS_H1    8691712    // H [b][s][256] fp32 : 2097152

// ---------------- output layout (floats) ----------------
#define OUT_MAIN   0          // [B,T,D]  8388608
#define OUT_LOGDUR 8388608    // [B,S]    8192
#define OUT_DUR    8396800    // [B,S]    8192
#define OUT_W      8404992    // [B,S,T]  16777216

// s_waitcnt imm: lgkmcnt(0), vmcnt(63)=no-wait, expcnt(7)=no-wait (gfx9 encoding)
#define WAIT_LGKM0_ONLY 0xC07F

__device__ __forceinline__ unsigned packh2(float a, float b) {
    U32H2 u; u.h = half2_t{(_Float16)a, (_Float16)b}; return u.u;
}

// quad_perm DPP lane swap within each 4-lane quad (VALU pipe)
template <int CTRL>
__device__ __forceinline__ float qswap(float v) {
    int i = __builtin_bit_cast(int, v);
    i = __builtin_amdgcn_update_dpp(0, i, CTRL, 0xf, 0xf, true);
    return __builtin_bit_cast(float, i);
}
#define QP_XOR1 0xB1  // [1,0,3,2]
#define QP_XOR2 0x4E  // [2,3,0,1]
#define QP_XOR3 0x1B  // [3,2,1,0]

// ============ prep: cumsum -> centers, copy duration ============
__global__ void prep_kernel(const float* __restrict__ dur, float* __restrict__ c,
                            float* __restrict__ out_dur) {
    int b = blockIdx.x;
    int s = threadIdx.x;
    __shared__ float sc[S_];
    float d = dur[b * S_ + s];
    sc[s] = d;
    __syncthreads();
    float v = d;
    for (int off = 1; off < S_; off <<= 1) {
        float add = (s >= off) ? sc[s - off] : 0.f;
        __syncthreads();
        v += add;
        sc[s] = v;
        __syncthreads();
    }
    c[b * S_ + s] = v - 0.5f * d;
    out_dur[b * S_ + s] = d;
}

// ============ Whh -> f16 pack body (quad-K-split layout) ============
// uidx = ((layer*2+dir)*512 + st)*64 + g*16 + kk ; st = e*4+q ; k2 = q*16+kk
__device__ void whh_pack_body(const float* __restrict__ Whh0, const float* __restrict__ Whh1,
                              unsigned* __restrict__ wpk, int gb) {
    int idx = gb * 256 + (int)threadIdx.x;  // 131072
    int kk = idx & 15, g = (idx >> 4) & 3, st = (idx >> 6) & 511;
    int dir = (idx >> 15) & 1, layer = (idx >> 16) & 1;
    int e = st >> 2, q = st & 3;
    int row = g * 128 + e;
    int k2 = q * 16 + kk;
    const float* W = layer ? Whh1 : Whh0;
    wpk[idx] = packh2(W[dir * 65536 + row * 128 + 2 * k2],
                      W[dir * 65536 + row * 128 + 2 * k2 + 1]);
}

// ============ wsum body: w2[b,t] = sum_s exp(-0.1 (t+1-c)^2) ============
__device__ void wsum_body(const float* __restrict__ c, float* __restrict__ w2, int gb) {
    int idx = gb * 4 + ((int)threadIdx.x >> 6);
    int lane = threadIdx.x & 63;
    int b = idx >> 11, t = idx & 2047;
    float tv = (float)(t + 1);
    const float* cb = c + b * 512;
    float sum = 0.f;
#pragma unroll
    for (int i = 0; i < 8; i++) {
        float d = tv - cb[lane + 64 * i];
        sum += __expf(-0.1f * d * d);
    }
#pragma unroll
    for (int off = 32; off; off >>= 1) sum += __shfl_xor(sum, off);
    if (lane == 0) w2[idx] = (sum == 0.f) ? 1.f : sum;
}

// ============ gemm body: Xg[((dir*512+s)*16+b)*512+jj] = A[m,:256].Wih[n,:256]+bias ============
#define BM 64
#define BN 64
#define BK 64
__device__ void gemm_xg_body(const float* __restrict__ A, const float* __restrict__ Bw,
                             const float* __restrict__ bias, float* __restrict__ Xg,
                             int bx, int by) {
    __shared__ float As[BK][BM + 4];
    __shared__ float Bs[BK][BN + 4];
    int tid = threadIdx.x;
    int m0 = bx * BM;
    int n0 = by * BN;
    int tm = tid >> 4, tn = tid & 15;
    float acc[4][4] = {};
    for (int k0 = 0; k0 < 256; k0 += BK) {
#pragma unroll
        for (int i = 0; i < 4; i++) {
            int p = tid + 256 * i;
            int m = p >> 4, kq = p & 15;
            float4 av = *reinterpret_cast<const float4*>(&A[(size_t)(m0 + m) * 256 + k0 + 4 * kq]);
            As[4 * kq + 0][m] = av.x; As[4 * kq + 1][m] = av.y;
            As[4 * kq + 2][m] = av.z; As[4 * kq + 3][m] = av.w;
            float4 bv = *reinterpret_cast<const float4*>(&Bw[(size_t)(n0 + m) * 256 + k0 + 4 * kq]);
            Bs[4 * kq + 0][m] = bv.x; Bs[4 * kq + 1][m] = bv.y;
            Bs[4 * kq + 2][m] = bv.z; Bs[4 * kq + 3][m] = bv.w;
        }
        __syncthreads();
#pragma unroll
        for (int k = 0; k < BK; k++) {
            float4 a4 = *reinterpret_cast<const float4*>(&As[k][4 * tm]);
            float4 b4 = *reinterpret_cast<const float4*>(&Bs[k][4 * tn]);
            float av[4] = {a4.x, a4.y, a4.z, a4.w};
            float bv[4] = {b4.x, b4.y, b4.z, b4.w};
#pragma unroll
            for (int i = 0; i < 4; i++)
#pragma unroll
                for (int j = 0; j < 4; j++) acc[i][j] += av[i] * bv[j];
        }
        __syncthreads();
    }
#pragma unroll
    for (int i = 0; i < 4; i++) {
        int m = m0 + 4 * tm + i;
        int b = m >> 9, s = m & 511;
#pragma unroll
        for (int jx = 0; jx < 4; jx++) {
            int n = n0 + 4 * tn + jx;
            int dir = n >> 9, jj = n & 511;
            Xg[((size_t)(dir * 512 + s) * 16 + b) * 512 + jj] = acc[i][jx] + bias[n];
        }
    }
}

// ============ stageA: gemm_xg L0 + whh_pack + wsum in one launch ============
__global__ __launch_bounds__(256) void stageA_kernel(const float* __restrict__ x,
                                                     const float* __restrict__ Wih0,
                                                     const float* __restrict__ b0,
                                                     float* __restrict__ Xg,
                                                     const float* __restrict__ Whh0,
                                                     const float* __restrict__ Whh1,
                                                     unsigned* __restrict__ wpk,
                                                     const float* __restrict__ c,
                                                     float* __restrict__ w2) {
    int blk = blockIdx.x;
    if (blk < 2048) {
        gemm_xg_body(x, Wih0, b0, Xg, blk & 127, blk >> 7);
    } else if (blk < 2560) {
        whh_pack_body(Whh0, Whh1, wpk, blk - 2048);
    } else {
        wsum_body(c, w2, blk - 2560);
    }
}

// ============ gemm_xg standalone (layer 1) ============
__global__ __launch_bounds__(256) void gemm_xg_kernel(const float* __restrict__ A,
                                                      const float* __restrict__ Bw,
                                                      const float* __restrict__ bias,
                                                      float* __restrict__ Xg) {
    gemm_xg_body(A, Bw, bias, Xg, blockIdx.x, blockIdx.y);
}

// ============ LSTM scan body: quad-K-split, pointer-bump, 2x unroll, lean VALU ============
// thread st = e*4+q: K-quarter q of gate rows {e,128+e,256+e,384+e}  [r11, proven 672us]
__device__ void lstm_scan_body(const float* __restrict__ Xg, const unsigned* __restrict__ wpk,
                               float* __restrict__ Hout, char* smem, int blk) {
    int dir = blk >> 4;
    int b = blk & 15;
    int st = threadIdx.x;
    int e = st >> 2, q = st & 3;

    // 16 uint4 = 64 weight VGPRs via opaque asm loads (residency proven r8/r10/r11)
    const unsigned* wq = wpk + ((size_t)dir * 512 + st) * 64;
    uint4 w0, w1, w2, w3, w4, w5, w6, w7, w8, w9, w10, w11, w12, w13, w14, w15;
#define WL(W, OFF) \
    asm volatile("global_load_dwordx4 %0, %1, off offset:" #OFF : "=v"(W) : "v"(wq) : "memory")
    WL(w0, 0);    WL(w1, 16);   WL(w2, 32);   WL(w3, 48);
    WL(w4, 64);   WL(w5, 80);   WL(w6, 96);   WL(w7, 112);
    WL(w8, 128);  WL(w9, 144);  WL(w10, 160); WL(w11, 176);
    WL(w12, 192); WL(w13, 208); WL(w14, 224); WL(w15, 240);
#undef WL
    asm volatile("s_waitcnt vmcnt(0)" ::: "memory");

    unsigned short* hb = (unsigned short*)smem;  // [2][128] f16
    if (st < 128) hb[st] = 0;

    // hoisted per-lane activation constants: act = am*sigma(am*g) + ab
    float am = (q == 2) ? 2.f : 1.f;
    float ab = (q == 2) ? -1.f : 0.f;

    // pointer-bump setup (no clamps; OOB prefetch stays inside d_ws, values unused)
    ptrdiff_t sstep = dir ? -8192 : 8192;        // floats per s-slice
    int s0 = dir ? 511 : 0;
    const float* xg_p = Xg + (size_t)dir * (512 * 16 * 512) + (size_t)b * 512 + q * 128 + e
                        + (size_t)s0 * 8192;
    float xg_cur = xg_p[0];
    float xg_n1 = xg_p[sstep];
    const float* xg_pre = xg_p + 2 * sstep;      // points at t+2 slice
    float* ho_p = Hout + ((size_t)b * 512 + s0) * 256 + dir * 128 + e;  // used by q==0
    ptrdiff_t hostep = dir ? -256 : 256;
    float c = 0.f;
    __syncthreads();

#define DOT4(ACC, WW, HH)                                                     \
        { U32H2 wa, wb, wc, wd, xa, xb, xc, xd;                               \
          wa.u = WW.x; wb.u = WW.y; wc.u = WW.z; wd.u = WW.w;                 \
          xa.u = HH.x; xb.u = HH.y; xc.u = HH.z; xd.u = HH.w;                 \
          ACC = __builtin_amdgcn_fdot2(xa.h, wa.h, ACC, false);               \
          ACC = __builtin_amdgcn_fdot2(xb.h, wb.h, ACC, false);               \
          ACC = __builtin_amdgcn_fdot2(xc.h, wc.h, ACC, false);               \
          ACC = __builtin_amdgcn_fdot2(xd.h, wd.h, ACC, false); }

#define SCAN_STEP(RDOFF, WROFF)                                               \
    {                                                                         \
        float xg_n2 = *xg_pre;                                                \
        xg_pre += sstep;                                                      \
        const uint4* h4 = (const uint4*)(hb + (RDOFF) + q * 32);              \
        uint4 h0 = h4[0], h1 = h4[1], h2 = h4[2], h3 = h4[3];                 \
        float a0 = 0.f, a1 = 0.f, a2 = 0.f, a3 = 0.f;                         \
        DOT4(a0, w0, h0)  DOT4(a0, w1, h1)  DOT4(a0, w2, h2)  DOT4(a0, w3, h3)\
        DOT4(a1, w4, h0)  DOT4(a1, w5, h1)  DOT4(a1, w6, h2)  DOT4(a1, w7, h3)\
        DOT4(a2, w8, h0)  DOT4(a2, w9, h1)  DOT4(a2, w10, h2) DOT4(a2, w11, h3)\
        DOT4(a3, w12, h0) DOT4(a3, w13, h1) DOT4(a3, w14, h2) DOT4(a3, w15, h3)\
        a0 += qswap<QP_XOR1>(a0); a0 += qswap<QP_XOR2>(a0);                   \
        a1 += qswap<QP_XOR1>(a1); a1 += qswap<QP_XOR2>(a1);                   \
        a2 += qswap<QP_XOR1>(a2); a2 += qswap<QP_XOR2>(a2);                   \
        a3 += qswap<QP_XOR1>(a3); a3 += qswap<QP_XOR2>(a3);                   \
        float gfull = (q == 0 ? a0 : q == 1 ? a1 : q == 2 ? a2 : a3) + xg_cur;\
        float sg = __builtin_amdgcn_rcpf(1.f + __expf(-(am * gfull)));        \
        float act = __builtin_fmaf(am, sg, ab);                               \
        float x1 = qswap<QP_XOR1>(act);                                       \
        float x2 = qswap<QP_XOR2>(act);                                       \
        float x3 = qswap<QP_XOR3>(act);                                       \
        if (q == 0) {                                                         \
            float cn = x1 * c + act * x2;                                     \
            c = cn;                                                           \
            float th = __builtin_fmaf(                                        \
                2.f, __builtin_amdgcn_rcpf(1.f + __expf(-2.f * cn)), -1.f);   \
            float h = x3 * th;                                                \
            UH16 hv; hv.f = (_Float16)h;                                      \
            hb[(WROFF) + e] = hv.u;                                           \
            *ho_p = h;                                                        \
        }                                                                     \
        ho_p += hostep;                                                       \
        __builtin_amdgcn_sched_barrier(0);                                    \
        __builtin_amdgcn_s_waitcnt(WAIT_LGKM0_ONLY);                          \
        __builtin_amdgcn_s_barrier();                                         \
        __builtin_amdgcn_sched_barrier(0);                                    \
        xg_cur = xg_n1;                                                       \
        xg_n1 = xg_n2;                                                        \
    }

    for (int it = 0; it < 256; it++) {
        SCAN_STEP(0, 128)
        SCAN_STEP(128, 0)
    }
#undef SCAN_STEP
#undef DOT4
}

// ============ w-write body (fused into layer-0 scan launch) ============
__device__ void wwrite_body(const float* __restrict__ c, const float* __restrict__ w2,
                            float* __restrict__ wout, int gb) {
    int base = (gb * 512 + (int)threadIdx.x) * 8;
    int t0 = base & 2047;
    int bs = base >> 11;
    int b = bs >> 9;
    float cv = c[bs];
    float4 w2a = *(const float4*)&w2[b * 2048 + t0];
    float4 w2b = *(const float4*)&w2[b * 2048 + t0 + 4];
    float r[8];
#pragma unroll
    for (int i = 0; i < 8; i++) {
        float d = (float)(t0 + 1 + i) - cv;
        r[i] = __expf(-0.1f * d * d);
    }
    float4 o1 = {r[0] / w2a.x, r[1] / w2a.y, r[2] / w2a.z, r[3] / w2a.w};
    float4 o2 = {r[4] / w2b.x, r[5] / w2b.y, r[6] / w2b.z, r[7] / w2b.w};
    *(float4*)&wout[base] = o1;
    *(float4*)&wout[base + 4] = o2;
}

// ============ einsum GEMM body: f16-pair fdot2, 128(t)x64(d) tile, K=512 ============
__device__ void gemm_out_body(const float* __restrict__ wmat, const float* __restrict__ x,
                              float* __restrict__ out, int gb, char* smem) {
    int tt = gb & 15, dd = (gb >> 4) & 3, b = gb >> 6;
    int m0 = tt * 128, n0 = dd * 64;
    unsigned* As2 = (unsigned*)smem;       // [32][136]
    unsigned* Bs2 = As2 + 32 * 136;        // [32][72]
    const float* wb = wmat + (size_t)b * (512 * 2048);
    const float* xb = x + (size_t)b * (512 * 256);
    int tid = threadIdx.x;
    int tm = tid >> 4, tn = tid & 15;
    float acc[4][4] = {};
    for (int k0 = 0; k0 < 512; k0 += 64) {
#pragma unroll
        for (int i = 0; i < 2; i++) {
            int p = tid + 512 * i;
            int k2 = p >> 5, mq = p & 31;
            float4 lo = *(const float4*)&wb[(size_t)(k0 + 2 * k2) * 2048 + m0 + 4 * mq];
            float4 hi = *(const float4*)&wb[(size_t)(k0 + 2 * k2 + 1) * 2048 + m0 + 4 * mq];
            uint4 o;
            o.x = packh2(lo.x, hi.x); o.y = packh2(lo.y, hi.y);
            o.z = packh2(lo.z, hi.z); o.w = packh2(lo.w, hi.w);
            *(uint4*)&As2[k2 * 136 + 4 * mq] = o;
        }
        {
            int k2 = tid >> 4, nq = tid & 15;
            float4 lo = *(const float4*)&xb[(size_t)(k0 + 2 * k2) * 256 + n0 + 4 * nq];
            float4 hi = *(const float4*)&xb[(size_t)(k0 + 2 * k2 + 1) * 256 + n0 + 4 * nq];
            uint4 o;
            o.x = packh2(lo.x, hi.x); o.y = packh2(lo.y, hi.y);
            o.z = packh2(lo.z, hi.z); o.w = packh2(lo.w, hi.w);
            *(uint4*)&Bs2[k2 * 72 + 4 * nq] = o;
        }
        __syncthreads();
#pragma unroll
        for (int k2 = 0; k2 < 32; k2++) {
            uint4 a4 = *(const uint4*)&As2[k2 * 136 + 4 * tm];
            uint4 b4 = *(const uint4*)&Bs2[k2 * 72 + 4 * tn];
            U32H2 aa0, aa1, aa2, aa3, bb0, bb1, bb2, bb3;
            aa0.u = a4.x; aa1.u = a4.y; aa2.u = a4.z; aa3.u = a4.w;
            bb0.u = b4.x; bb1.u = b4.y; bb2.u = b4.z; bb3.u = b4.w;
            half2_t av[4] = {aa0.h, aa1.h, aa2.h, aa3.h};
            half2_t bv[4] = {bb0.h, bb1.h, bb2.h, bb3.h};
#pragma unroll
            for (int i = 0; i < 4; i++)
#pragma unroll
                for (int j = 0; j < 4; j++)
                    acc[i][j] = __builtin_amdgcn_fdot2(av[i], bv[j], acc[i][j], false);
        }
        __syncthreads();
    }
#pragma unroll
    for (int i = 0; i < 4; i++) {
        int m = m0 + 4 * tm + i;
        float4 o = {acc[i][0], acc[i][1], acc[i][2], acc[i][3]};
        *(float4*)&out[((size_t)b * 2048 + m) * 256 + n0 + 4 * tn] = o;
    }
}

// ============ fused launches: occupancy target capped at 2 waves/EU ============
__global__ __launch_bounds__(512) __attribute__((amdgpu_waves_per_eu(2, 2)))
void fusedA_kernel(const float* __restrict__ Xg, const unsigned* __restrict__ wpk,
                   float* __restrict__ H1, const float* __restrict__ c,
                   const float* __restrict__ w2, float* __restrict__ out_w) {
    extern __shared__ char smem[];
    if (blockIdx.x < 32) lstm_scan_body(Xg, wpk, H1, smem, blockIdx.x);
    else wwrite_body(c, w2, out_w, blockIdx.x - 32);
}

__global__ __launch_bounds__(512) __attribute__((amdgpu_waves_per_eu(2, 2)))
void fusedB_kernel(const float* __restrict__ Xg, const unsigned* __restrict__ wpk,
                   float* __restrict__ H1, const float* __restrict__ wmat,
                   const float* __restrict__ x, float* __restrict__ out_main) {
    extern __shared__ char smem[];
    if (blockIdx.x < 32) lstm_scan_body(Xg, wpk, H1, smem, blockIdx.x);
    else gemm_out_body(wmat, x, out_main, blockIdx.x - 32, smem);
}

// ============ projection: log_dur (H1 [b][s][256]) ============
__global__ void proj_kernel(const float* __restrict__ H2, const float* __restrict__ pw,
                            const float* __restrict__ pb, const unsigned char* __restrict__ mask,
                            float* __restrict__ out) {
    int row = blockIdx.x * 4 + (threadIdx.x >> 6);
    int lane = threadIdx.x & 63;
    float4 h = *reinterpret_cast<const float4*>(&H2[(size_t)row * 256 + lane * 4]);
    float4 w = *reinterpret_cast<const float4*>(&pw[lane * 4]);
    float v = h.x * w.x + h.y * w.y + h.z * w.z + h.w * w.w;
#pragma unroll
    for (int off = 32; off; off >>= 1) v += __shfl_xor(v, off);
    if (lane == 0) {
        float r = v + pb[0];
        r = r > 0.f ? r : 0.f;
        if (mask[row]) r = 0.f;
        out[row] = r;
    }
}

extern "C" void kernel_launch(void* const* d_in, const int* in_sizes, int n_in,
                              void* d_out, int out_size, void* d_ws, size_t ws_size,
                              hipStream_t stream) {
    const float* x = (const float*)d_in[0];
    const unsigned char* mask = (const unsigned char*)d_in[1];
    const float* dur = (const float*)d_in[2];
    const float* Wih0 = (const float*)d_in[3];
    const float* Whh0 = (const float*)d_in[4];
    const float* b0 = (const float*)d_in[5];
    const float* Wih1 = (const float*)d_in[6];
    const float* Whh1 = (const float*)d_in[7];
    const float* b1 = (const float*)d_in[8];
    const float* pw = (const float*)d_in[9];
    const float* pb = (const float*)d_in[10];

    float* out = (float*)d_out;
    float* ws = (float*)d_ws;
    float* c = ws + WS_C;
    float* w2 = ws + WS_W2;
    unsigned* wpk = (unsigned*)(ws + WS_WPK);
    float* Xg = ws + WS_XG;
    float* H1 = ws + WS_H1;

    float* out_main = out + OUT_MAIN;
    float* out_logdur = out + OUT_LOGDUR;
    float* out_dur = out + OUT_DUR;
    float* out_w = out + OUT_W;

    // ---- prep: centers + duration copy ----
    prep_kernel<<<16, 512, 0, stream>>>(dur, c, out_dur);

    // ---- stageA: Xg gemm L0 + Whh pack + w2 sums in one launch ----
    stageA_kernel<<<2048 + 512 + 8192, 256, 0, stream>>>(x, Wih0, b0, Xg,
                                                         Whh0, Whh1, wpk, c, w2);

    // ---- layer 0: scan fused with w-write ----
    fusedA_kernel<<<32 + 4096, 512, 1024, stream>>>(Xg, wpk, H1, c, w2, out_w);

    // ---- layer 1: Xg gemm (A = H1, same row order), then scan fused with f16 einsum ----
    gemm_xg_kernel<<<dim3(128, 16), 256, 0, stream>>>(H1, Wih1, b1, Xg);
    fusedB_kernel<<<32 + 1024, 512, 26624, stream>>>(Xg, wpk + 65536, H1, out_w, x, out_main);

    // ---- projection ----
    proj_kernel<<<2048, 256, 0, stream>>>(H1, pw, pb, mask, out_logdur);
}